// Round 3
// baseline (698.982 us; speedup 1.0000x reference)
//
#include <hip/hip_runtime.h>
#include <hip/hip_bf16.h>

// Problem constants
#define BB 4
#define LL 2048
#define SS 2048
#define EE 1024
#define HH 16
#define MM (BB * LL)   // 8192 rows

#define LOG2E 1.44269504088896f

typedef unsigned short u16;
typedef unsigned int   u32;
typedef u16   u16x4  __attribute__((ext_vector_type(4)));
typedef u16   u16x8  __attribute__((ext_vector_type(8)));
typedef u32   u32x2  __attribute__((ext_vector_type(2)));
typedef float f32x4  __attribute__((ext_vector_type(4)));
typedef __bf16 bf16x8 __attribute__((ext_vector_type(8)));

__device__ __forceinline__ u16 f2bf(float x) {
    unsigned u = __float_as_uint(x);
    u += 0x7fffu + ((u >> 16) & 1u);       // RNE
    return (u16)(u >> 16);
}
__device__ __forceinline__ float bf2f(u16 b) {
    return __uint_as_float(((unsigned)b) << 16);
}
// pack bf16(e1)<<16 | bf16(e0), truncation, one v_perm_b32
__device__ __forceinline__ u32 pack_trunc(float e0, float e1) {
    return __builtin_amdgcn_perm(__float_as_uint(e1), __float_as_uint(e0), 0x07060302u);
}
// async global->LDS, 16B per lane, dst = wave-uniform base + lane*16
__device__ __forceinline__ void glds16(const u16* g, u16* l) {
    __builtin_amdgcn_global_load_lds(
        (const __attribute__((address_space(1))) unsigned int*)(size_t)g,
        (__attribute__((address_space(3))) unsigned int*)(unsigned int)(size_t)l,
        16, 0, 0);
}

// ---------------------------------------------------------------------------
__global__ __launch_bounds__(256) void f32_to_bf16_kernel(
    const float* __restrict__ in, u16* __restrict__ out)
{
    size_t idx = ((size_t)blockIdx.x * 256 + threadIdx.x) * 8;
    f32x4 a = *(const f32x4*)(in + idx);
    f32x4 b = *(const f32x4*)(in + idx + 4);
    u16x8 o;
#pragma unroll
    for (int j = 0; j < 4; j++) { o[j] = f2bf(a[j]); o[4 + j] = f2bf(b[j]); }
    *(u16x8*)(out + idx) = o;
}

// comb[l][s] = bf16(log2e * (bias + mask))
__global__ __launch_bounds__(256) void combine_bias_kernel(
    const float* __restrict__ bias, const float* __restrict__ mask,
    u16* __restrict__ comb)
{
    size_t idx = ((size_t)blockIdx.x * 256 + threadIdx.x) * 8;
    f32x4 a0 = *(const f32x4*)(bias + idx);
    f32x4 a1 = *(const f32x4*)(bias + idx + 4);
    f32x4 m0 = *(const f32x4*)(mask + idx);
    f32x4 m1 = *(const f32x4*)(mask + idx + 4);
    u16x8 o;
#pragma unroll
    for (int j = 0; j < 4; j++) {
        o[j]     = f2bf(LOG2E * (a0[j] + m0[j]));
        o[4 + j] = f2bf(LOG2E * (a1[j] + m1[j]));
    }
    *(u16x8*)(comb + idx) = o;
}

// ---------------------------------------------------------------------------
// C[m][n] = (sum_k A[m][k]*B[n][k] + bias) * scale.  A,B bf16 [rows][K].
// 128x128 tile, BK=64, global_load_lds staging, XOR-swizzled 16B chunks
// (LDS[row][c] = G[row][c ^ (row&7)], rows 128B unpadded -> 2-way free reads).
template <int BIASM, int OUTBF16>
__global__ __launch_bounds__(256, 3) void gemm_bt(
    const u16* __restrict__ A, const u16* __restrict__ B,
    const float* __restrict__ bias, void* __restrict__ Cp,
    int M, int N, int K, float scale)
{
    __shared__ __align__(16) u16 As[128 * 64];
    __shared__ __align__(16) u16 Bs[128 * 64];
    const int tid = threadIdx.x;
    const int lane = tid & 63, wave = tid >> 6;
    const int quad = lane >> 4, ln = lane & 15;
    const int wm = (wave & 1) * 64, wn = (wave >> 1) * 64;
    const int m0 = blockIdx.x * 128, n0 = blockIdx.y * 128;
    const int rl = lane >> 3, cc = lane & 7;
    const int sc = cc ^ rl;                    // swizzled 16B chunk (rl = row&7)

    f32x4 acc[4][4];
#pragma unroll
    for (int mt = 0; mt < 4; mt++)
#pragma unroll
        for (int nt = 0; nt < 4; nt++) acc[mt][nt] = (f32x4){0.f, 0.f, 0.f, 0.f};

    const int lnx = ln & 7;                    // frag-read XOR term

    for (int k0 = 0; k0 < K; k0 += 64) {
#pragma unroll
        for (int i = 0; i < 4; i++) {
            int ch = wave * 4 + i;             // 8-row group
            glds16(A + (size_t)(m0 + ch * 8 + rl) * K + k0 + sc * 8, As + ch * 512);
            glds16(B + (size_t)(n0 + ch * 8 + rl) * K + k0 + sc * 8, Bs + ch * 512);
        }
        __syncthreads();                       // vmcnt(0) drain + all waves staged

#pragma unroll
        for (int ks = 0; ks < 2; ks++) {
            bf16x8 af[4], bfg[4];
#pragma unroll
            for (int mt = 0; mt < 4; mt++) {
                int row = wm + mt * 16 + ln;
                af[mt] = *(const bf16x8*)(As + row * 64 + ((ks * 4 + quad) ^ lnx) * 8);
            }
#pragma unroll
            for (int nt = 0; nt < 4; nt++) {
                int row = wn + nt * 16 + ln;
                bfg[nt] = *(const bf16x8*)(Bs + row * 64 + ((ks * 4 + quad) ^ lnx) * 8);
            }
#pragma unroll
            for (int mt = 0; mt < 4; mt++)
#pragma unroll
                for (int nt = 0; nt < 4; nt++)
                    acc[mt][nt] = __builtin_amdgcn_mfma_f32_16x16x32_bf16(
                        af[mt], bfg[nt], acc[mt][nt], 0, 0, 0);
        }
        __syncthreads();                       // reads done before next overwrite
    }

#pragma unroll
    for (int mt = 0; mt < 4; mt++) {
        f32x4 bm;
        if (BIASM) bm = *(const f32x4*)(bias + m0 + wm + mt * 16 + quad * 4);
#pragma unroll
        for (int nt = 0; nt < 4; nt++) {
            int n = n0 + wn + nt * 16 + ln;
            float bn = BIASM ? 0.f : bias[n];
#pragma unroll
            for (int r = 0; r < 4; r++) {
                int m = m0 + wm + mt * 16 + quad * 4 + r;
                float val = (acc[mt][nt][r] + (BIASM ? bm[r] : bn)) * scale;
                if (OUTBF16) ((u16*)Cp)[(size_t)m * N + n] = f2bf(val);
                else         ((float*)Cp)[(size_t)m * N + n] = val;
            }
        }
    }
}

// ---------------------------------------------------------------------------
// Attention, barrier-free. Block = 128 q-rows of one (b,h); 4 waves x 32 q.
// S^T = K*Q^T with K-frags direct from global; softmax in exp2 domain
// (log2e pre-folded into q and comb); P^T in wave-private LDS rows;
// O^T = V^T*P with V-frags direct from global (vt = [feat][B*S]).
__global__ __launch_bounds__(256, 3) void attn_kernel(
    const u16* __restrict__ qb,   // [B,L,E] bf16, pre-scaled by 0.125*log2e
    const u16* __restrict__ kb,   // [B,S,E] bf16
    const u16* __restrict__ vt,   // [E][B*S] bf16 (row = h*64+d, col = b*SS+s)
    const u16* __restrict__ comb, // [L,S] bf16, log2e*(mask+bias)
    u16* __restrict__ attn)       // [B,L,E] bf16
{
    __shared__ __align__(16) u16 Ps[128 * 136];   // P^T [q_local][s_local]
    const int tid = threadIdx.x, lane = tid & 63, wave = tid >> 6;
    const int quad = lane >> 4, ln = lane & 15;
    const int bh = blockIdx.y, b = bh >> 4, h = bh & 15;
    const int q0 = blockIdx.x * 128;
    const int qloc0 = wave * 32;

    bf16x8 qf[2][2];
#pragma unroll
    for (int qg = 0; qg < 2; qg++)
#pragma unroll
        for (int ks = 0; ks < 2; ks++)
            qf[qg][ks] = *(const bf16x8*)(qb + (size_t)(b * LL + q0 + qloc0 + 16 * qg + ln) * EE
                                          + h * 64 + ks * 32 + quad * 8);

    const u16* kbase = kb + (size_t)b * SS * EE + h * 64;       // + (s)*EE + chunk
    const u16* vbase = vt + (size_t)(h * 64) * MM + b * SS;     // + d*MM + s
    const u16* cb0 = comb + (size_t)(q0 + qloc0 + ln) * SS + quad * 4;
    const u16* cb1 = cb0 + (size_t)16 * SS;

    f32x4 o[4][2];
#pragma unroll
    for (int mt = 0; mt < 4; mt++) { o[mt][0] = (f32x4){0,0,0,0}; o[mt][1] = (f32x4){0,0,0,0}; }
    float lsum0 = 0.f, lsum1 = 0.f;

    u16* prow0 = Ps + (qloc0 + ln) * 136;        // qg=0 row (wave-private)
    u16* prow1 = Ps + (qloc0 + 16 + ln) * 136;   // qg=1 row

    for (int s0 = 0; s0 < SS; s0 += 128) {
        // ---- QK + softmax, per 16-s strip ----
#pragma unroll
        for (int mt = 0; mt < 8; mt++) {
            const u16* ka = kbase + (size_t)(s0 + mt * 16 + ln) * EE;
            bf16x8 a0 = *(const bf16x8*)(ka + quad * 8);
            bf16x8 a1 = *(const bf16x8*)(ka + 32 + quad * 8);
#pragma unroll
            for (int qg = 0; qg < 2; qg++) {
                f32x4 z = (f32x4){0,0,0,0};
                z = __builtin_amdgcn_mfma_f32_16x16x32_bf16(a0, qf[qg][0], z, 0, 0, 0);
                z = __builtin_amdgcn_mfma_f32_16x16x32_bf16(a1, qf[qg][1], z, 0, 0, 0);
                u16x4 bv = *(const u16x4*)((qg ? cb1 : cb0) + s0 + mt * 16);
                float e0 = __builtin_amdgcn_exp2f(z[0] + bf2f(bv[0]));
                float e1 = __builtin_amdgcn_exp2f(z[1] + bf2f(bv[1]));
                float e2 = __builtin_amdgcn_exp2f(z[2] + bf2f(bv[2]));
                float e3 = __builtin_amdgcn_exp2f(z[3] + bf2f(bv[3]));
                if (qg == 0) lsum0 += (e0 + e1) + (e2 + e3);
                else         lsum1 += (e0 + e1) + (e2 + e3);
                u32x2 pk;
                pk[0] = pack_trunc(e0, e1);
                pk[1] = pack_trunc(e2, e3);
                *(u32x2*)((qg ? prow1 : prow0) + mt * 16 + quad * 4) = pk;
            }
        }

        // ---- PV: O^T[d][q] += V^T[d][s] * P[s][q] ----
#pragma unroll
        for (int ks = 0; ks < 4; ks++) {
            bf16x8 pf0 = *(const bf16x8*)(prow0 + ks * 32 + quad * 8);
            bf16x8 pf1 = *(const bf16x8*)(prow1 + ks * 32 + quad * 8);
#pragma unroll
            for (int mt = 0; mt < 4; mt++) {
                bf16x8 va = *(const bf16x8*)(vbase + (size_t)(mt * 16 + ln) * MM
                                             + s0 + ks * 32 + quad * 8);
                o[mt][0] = __builtin_amdgcn_mfma_f32_16x16x32_bf16(va, pf0, o[mt][0], 0, 0, 0);
                o[mt][1] = __builtin_amdgcn_mfma_f32_16x16x32_bf16(va, pf1, o[mt][1], 0, 0, 0);
            }
        }
    }

    // softmax denominator across quads
    lsum0 += __shfl_xor(lsum0, 16); lsum0 += __shfl_xor(lsum0, 32);
    lsum1 += __shfl_xor(lsum1, 16); lsum1 += __shfl_xor(lsum1, 32);
    float inv0 = 1.f / lsum0, inv1 = 1.f / lsum1;

    // O^T -> LDS (wave-private rows, [q][d]) -> coalesced store
#pragma unroll
    for (int mt = 0; mt < 4; mt++) {
        u16x4 p0, p1;
#pragma unroll
        for (int r = 0; r < 4; r++) { p0[r] = f2bf(o[mt][0][r] * inv0); p1[r] = f2bf(o[mt][1][r] * inv1); }
        *(u16x4*)(prow0 + mt * 16 + quad * 4) = p0;
        *(u16x4*)(prow1 + mt * 16 + quad * 4) = p1;
    }
#pragma unroll
    for (int i = 0; i < 4; i++) {
        int j = lane + 64 * i;                 // 256 chunks over wave's 32 rows
        int r = j >> 3, c = j & 7;
        u16x8 v = *(const u16x8*)(Ps + (qloc0 + r) * 136 + c * 8);
        *(u16x8*)(attn + (size_t)(b * LL + q0 + qloc0 + r) * EE + h * 64 + c * 8) = v;
    }
}

// ---------------------------------------------------------------------------
extern "C" void kernel_launch(void* const* d_in, const int* in_sizes, int n_in,
                              void* d_out, int out_size, void* d_ws, size_t ws_size,
                              hipStream_t stream)
{
    (void)in_sizes; (void)n_in; (void)out_size; (void)ws_size;
    const float* query     = (const float*)d_in[0];
    const float* key       = (const float*)d_in[1];
    const float* value     = (const float*)d_in[2];
    const float* attn_bias = (const float*)d_in[3];
    const float* attn_mask = (const float*)d_in[4];
    const float* Wqkv      = (const float*)d_in[5];
    const float* bqkv      = (const float*)d_in[6];
    const float* Wo        = (const float*)d_in[7];
    const float* bo        = (const float*)d_in[8];
    float* out = (float*)d_out;

    // workspace layout (~96 MB; k_bf aliases qin_bf, attnb aliases kin_bf)
    u16* wq_bf  = (u16*)d_ws;                      // 3*EE*EE
    u16* wo_bf  = wq_bf + 3 * EE * EE;             // EE*EE
    u16* comb   = wo_bf + EE * EE;                 // LL*SS
    u16* qin_bf = comb   + (size_t)LL * SS;        // MM*EE
    u16* kin_bf = qin_bf + (size_t)MM * EE;        // MM*EE
    u16* vin_bf = kin_bf + (size_t)MM * EE;        // MM*EE
    u16* q_bf   = vin_bf + (size_t)MM * EE;        // MM*EE
    u16* vtr    = q_bf   + (size_t)MM * EE;        // EE*MM
    u16* k_bf   = qin_bf;                          // alias: qin dead after Q-GEMM
    u16* attnb  = kin_bf;                          // alias: kin dead after K-GEMM

    f32_to_bf16_kernel<<<3 * EE * EE / 2048, 256, 0, stream>>>(Wqkv, wq_bf);
    f32_to_bf16_kernel<<<EE * EE / 2048, 256, 0, stream>>>(Wo, wo_bf);
    f32_to_bf16_kernel<<<(size_t)MM * EE / 2048, 256, 0, stream>>>(query, qin_bf);
    f32_to_bf16_kernel<<<(size_t)MM * EE / 2048, 256, 0, stream>>>(key, kin_bf);
    f32_to_bf16_kernel<<<(size_t)MM * EE / 2048, 256, 0, stream>>>(value, vin_bf);
    combine_bias_kernel<<<(LL * SS) / 2048, 256, 0, stream>>>(attn_bias, attn_mask, comb);

    dim3 gg(MM / 128, EE / 128);   // projections: M=8192, N=1024
    gemm_bt<0, 1><<<gg, 256, 0, stream>>>(qin_bf, wq_bf, bqkv, q_bf,
                                          MM, EE, EE, 0.125f * LOG2E);
    gemm_bt<0, 1><<<gg, 256, 0, stream>>>(kin_bf, wq_bf + EE * EE, bqkv + EE, k_bf,
                                          MM, EE, EE, 1.f);
    // V projection transposed: C[feat][b*S+s] = Wv·value^T  (bias over m)
    dim3 gv(EE / 128, MM / 128);
    gemm_bt<1, 1><<<gv, 256, 0, stream>>>(wq_bf + 2 * EE * EE, vin_bf, bqkv + 2 * EE, vtr,
                                          EE, MM, EE, 1.f);

    attn_kernel<<<dim3(LL / 128, BB * HH), 256, 0, stream>>>(q_bf, k_bf, vtr, comb, attnb);

    gemm_bt<0, 0><<<gg, 256, 0, stream>>>(attnb, wo_bf, bo, out, MM, EE, EE, 1.f);
}

// Round 4
// 446.120 us; speedup vs baseline: 1.5668x; 1.5668x over previous
//
#include <hip/hip_runtime.h>
#include <hip/hip_bf16.h>

// Problem constants
#define BB 4
#define LL 2048
#define SS 2048
#define EE 1024
#define HH 16
#define MM (BB * LL)   // 8192 rows

#define LOG2E 1.44269504088896f

typedef unsigned short u16;
typedef unsigned int   u32;
typedef u16   u16x4  __attribute__((ext_vector_type(4)));
typedef u16   u16x8  __attribute__((ext_vector_type(8)));
typedef u32   u32x2  __attribute__((ext_vector_type(2)));
typedef float f32x4  __attribute__((ext_vector_type(4)));
typedef __bf16 bf16x8 __attribute__((ext_vector_type(8)));

__device__ __forceinline__ u16 f2bf(float x) {
    unsigned u = __float_as_uint(x);
    u += 0x7fffu + ((u >> 16) & 1u);       // RNE
    return (u16)(u >> 16);
}
__device__ __forceinline__ float bf2f(u16 b) {
    return __uint_as_float(((unsigned)b) << 16);
}
// pack bf16(e1)<<16 | bf16(e0), truncation, one v_perm_b32
__device__ __forceinline__ u32 pack_trunc(float e0, float e1) {
    return __builtin_amdgcn_perm(__float_as_uint(e1), __float_as_uint(e0), 0x07060302u);
}
// async global->LDS, 16B per lane, dst = wave-uniform base + lane*16
__device__ __forceinline__ void glds16(const u16* g, u16* l) {
    __builtin_amdgcn_global_load_lds(
        (const __attribute__((address_space(1))) unsigned int*)(size_t)g,
        (__attribute__((address_space(3))) unsigned int*)(unsigned int)(size_t)l,
        16, 0, 0);
}

// ---------------------------------------------------------------------------
__global__ __launch_bounds__(256) void f32_to_bf16_kernel(
    const float* __restrict__ in, u16* __restrict__ out)
{
    size_t idx = ((size_t)blockIdx.x * 256 + threadIdx.x) * 8;
    f32x4 a = *(const f32x4*)(in + idx);
    f32x4 b = *(const f32x4*)(in + idx + 4);
    u16x8 o;
#pragma unroll
    for (int j = 0; j < 4; j++) { o[j] = f2bf(a[j]); o[4 + j] = f2bf(b[j]); }
    *(u16x8*)(out + idx) = o;
}

// comb[l][s] = bf16(log2e * (bias + mask))
__global__ __launch_bounds__(256) void combine_bias_kernel(
    const float* __restrict__ bias, const float* __restrict__ mask,
    u16* __restrict__ comb)
{
    size_t idx = ((size_t)blockIdx.x * 256 + threadIdx.x) * 8;
    f32x4 a0 = *(const f32x4*)(bias + idx);
    f32x4 a1 = *(const f32x4*)(bias + idx + 4);
    f32x4 m0 = *(const f32x4*)(mask + idx);
    f32x4 m1 = *(const f32x4*)(mask + idx + 4);
    u16x8 o;
#pragma unroll
    for (int j = 0; j < 4; j++) {
        o[j]     = f2bf(LOG2E * (a0[j] + m0[j]));
        o[4 + j] = f2bf(LOG2E * (a1[j] + m1[j]));
    }
    *(u16x8*)(comb + idx) = o;
}

// ---------------------------------------------------------------------------
// C[m][n] = (sum_k A[m][k]*B[n][k] + bias) * scale.  A,B bf16 [rows][K].
// 128x128 tile, BK=64, global_load_lds staging, XOR-swizzled 16B chunks.
template <int BIASM, int OUTBF16>
__global__ __launch_bounds__(256, 3) void gemm_bt(
    const u16* __restrict__ A, const u16* __restrict__ B,
    const float* __restrict__ bias, void* __restrict__ Cp,
    int M, int N, int K, float scale)
{
    __shared__ __align__(16) u16 As[128 * 64];
    __shared__ __align__(16) u16 Bs[128 * 64];
    const int tid = threadIdx.x;
    const int lane = tid & 63, wave = tid >> 6;
    const int quad = lane >> 4, ln = lane & 15;
    const int wm = (wave & 1) * 64, wn = (wave >> 1) * 64;
    const int m0 = blockIdx.x * 128, n0 = blockIdx.y * 128;
    const int rl = lane >> 3, cc = lane & 7;
    const int sc = cc ^ rl;                    // swizzled 16B chunk (rl = row&7)

    f32x4 acc[4][4];
#pragma unroll
    for (int mt = 0; mt < 4; mt++)
#pragma unroll
        for (int nt = 0; nt < 4; nt++) acc[mt][nt] = (f32x4){0.f, 0.f, 0.f, 0.f};

    const int lnx = ln & 7;                    // frag-read XOR term

    for (int k0 = 0; k0 < K; k0 += 64) {
#pragma unroll
        for (int i = 0; i < 4; i++) {
            int ch = wave * 4 + i;             // 8-row group
            glds16(A + (size_t)(m0 + ch * 8 + rl) * K + k0 + sc * 8, As + ch * 512);
            glds16(B + (size_t)(n0 + ch * 8 + rl) * K + k0 + sc * 8, Bs + ch * 512);
        }
        __syncthreads();                       // vmcnt(0) drain + all waves staged

#pragma unroll
        for (int ks = 0; ks < 2; ks++) {
            bf16x8 af[4], bfg[4];
#pragma unroll
            for (int mt = 0; mt < 4; mt++) {
                int row = wm + mt * 16 + ln;
                af[mt] = *(const bf16x8*)(As + row * 64 + ((ks * 4 + quad) ^ lnx) * 8);
            }
#pragma unroll
            for (int nt = 0; nt < 4; nt++) {
                int row = wn + nt * 16 + ln;
                bfg[nt] = *(const bf16x8*)(Bs + row * 64 + ((ks * 4 + quad) ^ lnx) * 8);
            }
#pragma unroll
            for (int mt = 0; mt < 4; mt++)
#pragma unroll
                for (int nt = 0; nt < 4; nt++)
                    acc[mt][nt] = __builtin_amdgcn_mfma_f32_16x16x32_bf16(
                        af[mt], bfg[nt], acc[mt][nt], 0, 0, 0);
        }
        __syncthreads();                       // reads done before next overwrite
    }

#pragma unroll
    for (int mt = 0; mt < 4; mt++) {
        f32x4 bm;
        if (BIASM) bm = *(const f32x4*)(bias + m0 + wm + mt * 16 + quad * 4);
#pragma unroll
        for (int nt = 0; nt < 4; nt++) {
            int n = n0 + wn + nt * 16 + ln;
            float bn = BIASM ? 0.f : bias[n];
#pragma unroll
            for (int r = 0; r < 4; r++) {
                int m = m0 + wm + mt * 16 + quad * 4 + r;
                float val = (acc[mt][nt][r] + (BIASM ? bm[r] : bn)) * scale;
                if (OUTBF16) ((u16*)Cp)[(size_t)m * N + n] = f2bf(val);
                else         ((float*)Cp)[(size_t)m * N + n] = val;
            }
        }
    }
}

// ---------------------------------------------------------------------------
// Attention: per block 128 q-rows of one (b,h); 4 waves x 32 q.
// R2 structure (LDS staging + reg prefetch) with exp2-domain softmax,
// perm-packed P, and denominator accumulated via ones-row MFMA.
__global__ __launch_bounds__(256, 2) void attn_kernel(
    const u16* __restrict__ qb,   // [B,L,E] bf16, pre-scaled by 0.125*log2e
    const u16* __restrict__ kb,   // [B,S,E] bf16
    const u16* __restrict__ vt,   // [E][B*S] bf16 (row = h*64+d, col = b*SS+s)
    const u16* __restrict__ comb, // [L,S] bf16, log2e*(mask+bias)
    u16* __restrict__ attn)       // [B,L,E] bf16
{
    __shared__ __align__(16) u16 KPs[128 * 136];  // union: K tile (stride 72) / P^T (stride 136)
    __shared__ __align__(16) u16 Vs[64 * 136];    // V^T tile [d][s]
    const int tid = threadIdx.x, lane = tid & 63, wave = tid >> 6;
    const int quad = lane >> 4, ln = lane & 15;
    const int bh = blockIdx.y, b = bh >> 4, h = bh & 15;
    const int q0 = blockIdx.x * 128;
    const int qloc0 = wave * 32;

    bf16x8 qf[2][2];
#pragma unroll
    for (int qg = 0; qg < 2; qg++)
#pragma unroll
        for (int ks = 0; ks < 2; ks++)
            qf[qg][ks] = *(const bf16x8*)(qb + (size_t)(b * LL + q0 + qloc0 + 16 * qg + ln) * EE
                                          + h * 64 + ks * 32 + quad * 8);

    bf16x8 ones;
#pragma unroll
    for (int j = 0; j < 8; j++) ones[j] = (__bf16)1.0f;

    const u16* vbase = vt + (size_t)(h * 64) * MM + b * SS;
    const u16* cb0 = comb + (size_t)(q0 + qloc0 + ln) * SS + quad * 4;
    const u16* cb1 = cb0 + (size_t)16 * SS;

    f32x4 o[4][2];
#pragma unroll
    for (int mt = 0; mt < 4; mt++) { o[mt][0] = (f32x4){0,0,0,0}; o[mt][1] = (f32x4){0,0,0,0}; }
    f32x4 osum[2];
    osum[0] = (f32x4){0,0,0,0}; osum[1] = (f32x4){0,0,0,0};

    u16x8 kreg[4], vreg[4];
    auto load_kv = [&](int s0) {
#pragma unroll
        for (int i = 0; i < 4; i++) {
            int chunk = tid + 256 * i, row = chunk >> 3, c = chunk & 7;   // 128 x 8
            kreg[i] = *(const u16x8*)(kb + (size_t)(b * SS + s0 + row) * EE + h * 64 + c * 8);
        }
#pragma unroll
        for (int i = 0; i < 4; i++) {
            int chunk = tid + 256 * i, row = chunk >> 4, c = chunk & 15;  // 64 x 16
            vreg[i] = *(const u16x8*)(vbase + (size_t)row * MM + s0 + c * 8);
        }
    };
    load_kv(0);

    u16* prow0 = KPs + (qloc0 + ln) * 136;        // qg=0 row (wave-private)
    u16* prow1 = KPs + (qloc0 + 16 + ln) * 136;   // qg=1 row

    for (int s0 = 0; s0 < SS; s0 += 128) {
        __syncthreads();                           // prev iter's P/V LDS reads done
#pragma unroll
        for (int i = 0; i < 4; i++) {              // K tile -> union (stride 72)
            int chunk = tid + 256 * i, row = chunk >> 3, c = chunk & 7;
            *(u16x8*)(KPs + row * 72 + c * 8) = kreg[i];
        }
#pragma unroll
        for (int i = 0; i < 4; i++) {              // V^T tile
            int chunk = tid + 256 * i, row = chunk >> 4, c = chunk & 15;
            *(u16x8*)(Vs + row * 136 + c * 8) = vreg[i];
        }
        __syncthreads();

        if (s0 + 128 < SS) load_kv(s0 + 128);      // prefetch next K/V into regs

        // ---- S^T = K*Q^T, exp2 softmax, pack -> p regs (per strip) ----
        u32x2 p[8][2];
#pragma unroll
        for (int mt = 0; mt < 8; mt++) {
            bf16x8 a0 = *(const bf16x8*)(KPs + (mt * 16 + ln) * 72 + quad * 8);
            bf16x8 a1 = *(const bf16x8*)(KPs + (mt * 16 + ln) * 72 + 32 + quad * 8);
#pragma unroll
            for (int qg = 0; qg < 2; qg++) {
                f32x4 z = (f32x4){0,0,0,0};
                z = __builtin_amdgcn_mfma_f32_16x16x32_bf16(a0, qf[qg][0], z, 0, 0, 0);
                z = __builtin_amdgcn_mfma_f32_16x16x32_bf16(a1, qf[qg][1], z, 0, 0, 0);
                u16x4 bv = *(const u16x4*)((qg ? cb1 : cb0) + s0 + mt * 16);
                float e0 = __builtin_amdgcn_exp2f(z[0] + bf2f(bv[0]));
                float e1 = __builtin_amdgcn_exp2f(z[1] + bf2f(bv[1]));
                float e2 = __builtin_amdgcn_exp2f(z[2] + bf2f(bv[2]));
                float e3 = __builtin_amdgcn_exp2f(z[3] + bf2f(bv[3]));
                p[mt][qg][0] = pack_trunc(e0, e1);
                p[mt][qg][1] = pack_trunc(e2, e3);
            }
        }

        __syncthreads();                           // all waves done reading K tile

#pragma unroll
        for (int mt = 0; mt < 8; mt++) {           // P^T -> union (stride 136), wave-private rows
            *(u32x2*)(prow0 + mt * 16 + quad * 4) = p[mt][0];
            *(u32x2*)(prow1 + mt * 16 + quad * 4) = p[mt][1];
        }

        // ---- PV: O^T[d][q] += V^T[d][s]*P[s][q]; denominator via ones-row ----
#pragma unroll
        for (int ks = 0; ks < 4; ks++) {
            bf16x8 pf0 = *(const bf16x8*)(prow0 + ks * 32 + quad * 8);
            bf16x8 pf1 = *(const bf16x8*)(prow1 + ks * 32 + quad * 8);
#pragma unroll
            for (int mt = 0; mt < 4; mt++) {
                bf16x8 a = *(const bf16x8*)(Vs + (mt * 16 + ln) * 136 + ks * 32 + quad * 8);
                o[mt][0] = __builtin_amdgcn_mfma_f32_16x16x32_bf16(a, pf0, o[mt][0], 0, 0, 0);
                o[mt][1] = __builtin_amdgcn_mfma_f32_16x16x32_bf16(a, pf1, o[mt][1], 0, 0, 0);
            }
            osum[0] = __builtin_amdgcn_mfma_f32_16x16x32_bf16(ones, pf0, osum[0], 0, 0, 0);
            osum[1] = __builtin_amdgcn_mfma_f32_16x16x32_bf16(ones, pf1, osum[1], 0, 0, 0);
        }
    }

    // softmax denominator: all 4 rows of osum identical; col = this lane's q
    float inv0 = 1.f / osum[0][0];
    float inv1 = 1.f / osum[1][0];

    // O^T -> LDS (wave-private rows, [q][d]) -> coalesced store
#pragma unroll
    for (int mt = 0; mt < 4; mt++) {
        u16x4 p0, p1;
#pragma unroll
        for (int r = 0; r < 4; r++) { p0[r] = f2bf(o[mt][0][r] * inv0); p1[r] = f2bf(o[mt][1][r] * inv1); }
        *(u16x4*)(prow0 + mt * 16 + quad * 4) = p0;
        *(u16x4*)(prow1 + mt * 16 + quad * 4) = p1;
    }
#pragma unroll
    for (int i = 0; i < 4; i++) {
        int j = lane + 64 * i;                 // 256 chunks over wave's 32 rows
        int r = j >> 3, c = j & 7;
        u16x8 v = *(const u16x8*)(KPs + (qloc0 + r) * 136 + c * 8);
        *(u16x8*)(attn + (size_t)(b * LL + q0 + qloc0 + r) * EE + h * 64 + c * 8) = v;
    }
}

// ---------------------------------------------------------------------------
extern "C" void kernel_launch(void* const* d_in, const int* in_sizes, int n_in,
                              void* d_out, int out_size, void* d_ws, size_t ws_size,
                              hipStream_t stream)
{
    (void)in_sizes; (void)n_in; (void)out_size; (void)ws_size;
    const float* query     = (const float*)d_in[0];
    const float* key       = (const float*)d_in[1];
    const float* value     = (const float*)d_in[2];
    const float* attn_bias = (const float*)d_in[3];
    const float* attn_mask = (const float*)d_in[4];
    const float* Wqkv      = (const float*)d_in[5];
    const float* bqkv      = (const float*)d_in[6];
    const float* Wo        = (const float*)d_in[7];
    const float* bo        = (const float*)d_in[8];
    float* out = (float*)d_out;

    // workspace layout (~96 MB; k_bf aliases qin_bf, attnb aliases kin_bf)
    u16* wq_bf  = (u16*)d_ws;                      // 3*EE*EE
    u16* wo_bf  = wq_bf + 3 * EE * EE;             // EE*EE
    u16* comb   = wo_bf + EE * EE;                 // LL*SS
    u16* qin_bf = comb   + (size_t)LL * SS;        // MM*EE
    u16* kin_bf = qin_bf + (size_t)MM * EE;        // MM*EE
    u16* vin_bf = kin_bf + (size_t)MM * EE;        // MM*EE
    u16* q_bf   = vin_bf + (size_t)MM * EE;        // MM*EE
    u16* vtr    = q_bf   + (size_t)MM * EE;        // EE*MM
    u16* k_bf   = qin_bf;                          // alias: qin dead after Q-GEMM
    u16* attnb  = kin_bf;                          // alias: kin dead after K-GEMM

    f32_to_bf16_kernel<<<3 * EE * EE / 2048, 256, 0, stream>>>(Wqkv, wq_bf);
    f32_to_bf16_kernel<<<EE * EE / 2048, 256, 0, stream>>>(Wo, wo_bf);
    f32_to_bf16_kernel<<<(size_t)MM * EE / 2048, 256, 0, stream>>>(query, qin_bf);
    f32_to_bf16_kernel<<<(size_t)MM * EE / 2048, 256, 0, stream>>>(key, kin_bf);
    f32_to_bf16_kernel<<<(size_t)MM * EE / 2048, 256, 0, stream>>>(value, vin_bf);
    combine_bias_kernel<<<(LL * SS) / 2048, 256, 0, stream>>>(attn_bias, attn_mask, comb);

    dim3 gg(MM / 128, EE / 128);   // projections: M=8192, N=1024
    gemm_bt<0, 1><<<gg, 256, 0, stream>>>(qin_bf, wq_bf, bqkv, q_bf,
                                          MM, EE, EE, 0.125f * LOG2E);
    gemm_bt<0, 1><<<gg, 256, 0, stream>>>(kin_bf, wq_bf + EE * EE, bqkv + EE, k_bf,
                                          MM, EE, EE, 1.f);
    // V projection transposed: C[feat][b*S+s] = Wv·value^T  (bias over m)
    dim3 gv(EE / 128, MM / 128);
    gemm_bt<1, 1><<<gv, 256, 0, stream>>>(wq_bf + 2 * EE * EE, vin_bf, bqkv + 2 * EE, vtr,
                                          EE, MM, EE, 1.f);

    attn_kernel<<<dim3(LL / 128, BB * HH), 256, 0, stream>>>(q_bf, k_bf, vtr, comb, attnb);

    gemm_bt<0, 0><<<gg, 256, 0, stream>>>(attnb, wo_bf, bo, out, MM, EE, EE, 1.f);
}